// Round 1
// baseline (12256.248 us; speedup 1.0000x reference)
//
#include <hip/hip_runtime.h>
#include <hip/hip_fp16.h>

// GRU stack: B=64, T=256, F=256, U=1024, 3 layers, reset_after=True.
// d_in order (setup_inputs dict order):
//   [0]=inputs, then per layer l: [1+4l]=state_l, [2+4l]=W_l, [3+4l]=U_l, [4+4l]=b_l
// d_out: x[64,256,1024] f32, then s0,s1,s2 [64,1024] f32 each.

typedef _Float16 half8 __attribute__((ext_vector_type(8)));
typedef float f32x4 __attribute__((ext_vector_type(4)));

#define TSTEPS 256
#define UDIM 1024
#define G3U 3072
#define GRIDB 64

__device__ __forceinline__ f32x4 mfma16(half8 a, half8 b, f32x4 c) {
    return __builtin_amdgcn_mfma_f32_16x16x32_f16(a, b, c, 0, 0, 0);
}

// agent-scope (coherence-point) 16B load as 2x8B atomic loads: bypasses the
// non-coherent per-XCD L2 so cross-block h updates are always seen.
__device__ __forceinline__ half8 load_h_agent(const _Float16* p) {
    union { unsigned long long u[2]; half8 h; } un;
    const unsigned long long* q = (const unsigned long long*)p;
    un.u[0] = __hip_atomic_load(q,     __ATOMIC_RELAXED, __HIP_MEMORY_SCOPE_AGENT);
    un.u[1] = __hip_atomic_load(q + 1, __ATOMIC_RELAXED, __HIP_MEMORY_SCOPE_AGENT);
    return un.h;
}

__global__ void f32_to_f16(const float* __restrict__ src, _Float16* __restrict__ dst, int n) {
    int i = blockIdx.x * blockDim.x + threadIdx.x;
    int st = gridDim.x * blockDim.x;
    for (; i < n; i += st) dst[i] = (_Float16)src[i];
}

// Pack [W; Ur] (rows = k, cols = gate col) into MFMA B-fragment order:
// Bp[nt][kc][lane][8] with element = B[kc*32 + (lane>>4)*8 + i][nt*16 + (lane&15)]
__global__ void pack_weights(const float* __restrict__ W, const float* __restrict__ Ur,
                             _Float16* __restrict__ Bp, int KIN, int KC) {
    int idx = blockIdx.x * blockDim.x + threadIdx.x;
    int total = 192 * KC * 64;
    int st = gridDim.x * blockDim.x;
    for (; idx < total; idx += st) {
        int lane = idx & 63;
        int kc = (idx >> 6) % KC;
        int nt = idx / (KC * 64);
        int col = nt * 16 + (lane & 15);
        int k0 = kc * 32 + (lane >> 4) * 8;
        half8 v;
#pragma unroll
        for (int i = 0; i < 8; ++i) {
            int k = k0 + i;
            float f = (k < KIN) ? W[(size_t)k * G3U + col]
                                : Ur[(size_t)(k - KIN) * G3U + col];
            v[i] = (_Float16)f;
        }
        *(half8*)(Bp + (size_t)idx * 8) = v;
    }
}

// Persistent per-layer GRU kernel. 64 blocks x 512 threads (8 waves).
// Block b owns gate columns {j, U+j, 2U+j} for j in [16b, 16b+16) for ALL 64
// batch rows -> it alone produces its 16-col slice of new h => 1 barrier/step.
// Waves split K 8-ways; partials reduced through LDS. h master state lives in
// f32 registers of waves 0..3 (wave w = batch rows [16w,16w+16)).
__global__ __launch_bounds__(512, 1) void gru_layer(
    const _Float16* __restrict__ xcur,  // [B, T, KIN] fp16
    const _Float16* __restrict__ h0h,   // [B, U] fp16 initial state
    const float* __restrict__ state,    // [B, U] f32 initial state
    const _Float16* __restrict__ Bp,    // packed [192][KC][64][8]
    const float* __restrict__ bias,     // [2][3072] f32
    _Float16* __restrict__ yown,        // [B, T, U] fp16 layer output (h source)
    float* __restrict__ fxout,          // final layer: d_out x area, else null
    float* __restrict__ sout,           // d_out state slot [B, U]
    unsigned* cnt, int KIN)
{
    const int tid = threadIdx.x;
    const int lane = tid & 63;
    const int wid = tid >> 6;          // 0..7: K-split index
    const int blk = blockIdx.x;        // 0..63: column group
    const int col = lane & 15;
    const int lrow = lane >> 4;        // 0..3
    const int klane0 = lrow * 8;       // A/B fragment k offset for this lane
    const int j = blk * 16 + col;      // owned hidden unit column
    const int KC = (KIN + UDIM) >> 5;  // total K chunks (40 or 64)
    const int KCW = KC >> 3;           // chunks per wave
    const int ck0 = wid * KCW, ck1 = ck0 + KCW;
    const int KINC = KIN >> 5;         // x-part chunk count

    __shared__ f32x4 red[8][4][2][64]; // 64 KiB reduction buffer

    const float b0z = bias[j],           b1z = bias[G3U + j];
    const float b0r = bias[UDIM + j],    b1r = bias[G3U + UDIM + j];
    const float b0h = bias[2*UDIM + j],  b1h = bias[G3U + 2*UDIM + j];

    float hreg[4] = {0.f, 0.f, 0.f, 0.f};
    if (wid < 4) {
#pragma unroll
        for (int e = 0; e < 4; ++e) {
            int m = wid * 16 + lrow * 4 + e;  // D row = (lane>>4)*4 + reg
            hreg[e] = state[(size_t)m * UDIM + j];
        }
    }

    const _Float16* bpz = Bp + (size_t)(blk)       * KC * 512 + lane * 8;
    const _Float16* bpr = Bp + (size_t)(64 + blk)  * KC * 512 + lane * 8;
    const _Float16* bph = Bp + (size_t)(128 + blk) * KC * 512 + lane * 8;

    for (int t = 0; t < TSTEPS; ++t) {
        f32x4 accz[4], accr[4], acchx[4], acchr[4];
#pragma unroll
        for (int m4 = 0; m4 < 4; ++m4) {
            accz[m4] = (f32x4){0.f,0.f,0.f,0.f};
            accr[m4] = (f32x4){0.f,0.f,0.f,0.f};
            acchx[m4] = (f32x4){0.f,0.f,0.f,0.f};
            acchr[m4] = (f32x4){0.f,0.f,0.f,0.f};
        }
        const _Float16* xr[4];
        const _Float16* hr[4];
#pragma unroll
        for (int m4 = 0; m4 < 4; ++m4) {
            int rm = m4 * 16 + (lane & 15);   // A row = lane%16
            xr[m4] = xcur + ((size_t)rm * TSTEPS + t) * KIN + klane0;
            hr[m4] = (t == 0) ? (h0h + (size_t)rm * UDIM + klane0)
                              : (yown + ((size_t)rm * TSTEPS + (t - 1)) * UDIM + klane0);
        }
        // x-part chunks (normal cached loads; acchx gets the h-gate x term)
        int cxe = ck1 < KINC ? ck1 : KINC;
#pragma unroll 2
        for (int ck = ck0; ck < cxe; ++ck) {
            half8 bz = *(const half8*)(bpz + (size_t)ck * 512);
            half8 br = *(const half8*)(bpr + (size_t)ck * 512);
            half8 bh = *(const half8*)(bph + (size_t)ck * 512);
            int off = ck * 32;
#pragma unroll
            for (int m4 = 0; m4 < 4; ++m4) {
                half8 a = *(const half8*)(xr[m4] + off);
                accz[m4]  = mfma16(a, bz, accz[m4]);
                accr[m4]  = mfma16(a, br, accr[m4]);
                acchx[m4] = mfma16(a, bh, acchx[m4]);
            }
        }
        // h-part chunks (agent-scope loads; acchr gets the h-gate rec term)
        int chs = ck0 > KINC ? ck0 : KINC;
#pragma unroll 2
        for (int ck = chs; ck < ck1; ++ck) {
            half8 bz = *(const half8*)(bpz + (size_t)ck * 512);
            half8 br = *(const half8*)(bpr + (size_t)ck * 512);
            half8 bh = *(const half8*)(bph + (size_t)ck * 512);
            int off = (ck - KINC) * 32;
#pragma unroll
            for (int m4 = 0; m4 < 4; ++m4) {
                half8 a = load_h_agent(hr[m4] + off);
                accz[m4]  = mfma16(a, bz, accz[m4]);
                accr[m4]  = mfma16(a, br, accr[m4]);
                acchr[m4] = mfma16(a, bh, acchr[m4]);
            }
        }

        // 8-way cross-wave reduction in two 64KB-buffer passes
        f32x4 fz = {0.f,0.f,0.f,0.f}, fr = {0.f,0.f,0.f,0.f};
        f32x4 fhx = {0.f,0.f,0.f,0.f}, fhr = {0.f,0.f,0.f,0.f};
        for (int p = 0; p < 2; ++p) {
#pragma unroll
            for (int m4 = 0; m4 < 4; ++m4) {
                red[wid][m4][0][lane] = p ? acchx[m4] : accz[m4];
                red[wid][m4][1][lane] = p ? acchr[m4] : accr[m4];
            }
            __syncthreads();
            if (wid < 4) {
                f32x4 s0 = {0.f,0.f,0.f,0.f}, s1 = {0.f,0.f,0.f,0.f};
#pragma unroll
                for (int s = 0; s < 8; ++s) {
                    s0 += red[s][wid][0][lane];
                    s1 += red[s][wid][1][lane];
                }
                if (p == 0) { fz = s0; fr = s1; } else { fhx = s0; fhr = s1; }
            }
            __syncthreads();
        }

        if (wid < 4) {
#pragma unroll
            for (int e = 0; e < 4; ++e) {
                float zp = fz[e] + b0z + b1z;
                float rp = fr[e] + b0r + b1r;
                float z = 1.f / (1.f + expf(-zp));
                float r = 1.f / (1.f + expf(-rp));
                float hh = tanhf(fhx[e] + b0h + r * (fhr[e] + b1h));
                float hn = z * hreg[e] + (1.f - z) * hh;
                hreg[e] = hn;
                int m = wid * 16 + lrow * 4 + e;
                size_t yi = ((size_t)m * TSTEPS + t) * UDIM + j;
                union { _Float16 f; unsigned short u; } cv;
                cv.f = (_Float16)hn;
                // pack 2 adjacent cols into one 4B agent store (sub-4B atomic
                // stores are not reliably supported)
                unsigned pu = (unsigned)(unsigned short)__shfl_xor((int)(unsigned)cv.u, 1, 64);
                if (!(col & 1)) {
                    unsigned val = ((unsigned)cv.u) | (pu << 16);
                    __hip_atomic_store((unsigned*)(yown + yi), val,
                                       __ATOMIC_RELAXED, __HIP_MEMORY_SCOPE_AGENT);
                }
                if (fxout) fxout[yi] = hn;
                if (t == TSTEPS - 1) sout[(size_t)m * UDIM + j] = hn;
            }
        }

        // one grid barrier per timestep (skip after last step)
        if (t < TSTEPS - 1) {
            __syncthreads();  // drains vmcnt for all waves (stores visible at L3)
            if (tid == 0) {
                __hip_atomic_fetch_add(cnt, 1u, __ATOMIC_RELEASE, __HIP_MEMORY_SCOPE_AGENT);
                unsigned tgt = (unsigned)GRIDB * (unsigned)(t + 1);
                while (__hip_atomic_load(cnt, __ATOMIC_RELAXED, __HIP_MEMORY_SCOPE_AGENT) < tgt)
                    __builtin_amdgcn_s_sleep(2);
            }
            __syncthreads();
        }
    }
}

extern "C" void kernel_launch(void* const* d_in, const int* in_sizes, int n_in,
                              void* d_out, int out_size, void* d_ws, size_t ws_size,
                              hipStream_t stream) {
    (void)in_sizes; (void)n_in; (void)out_size; (void)ws_size;

    char* ws = (char*)d_ws;
    size_t off = 0;
    auto take = [&](size_t bytes) -> char* {
        char* p = ws + off;
        off += (bytes + 255) & ~(size_t)255;
        return p;
    };
    unsigned* counters = (unsigned*)take(1024);
    _Float16* h0h0 = (_Float16*)take((size_t)65536 * 2);
    _Float16* h0h1 = (_Float16*)take((size_t)65536 * 2);
    _Float16* h0h2 = (_Float16*)take((size_t)65536 * 2);
    _Float16* xin  = (_Float16*)take((size_t)4194304 * 2);     // [64,256,256]
    _Float16* y0   = (_Float16*)take((size_t)16777216 * 2);    // [64,256,1024]
    _Float16* y1   = (_Float16*)take((size_t)16777216 * 2);
    _Float16* y2   = (_Float16*)take((size_t)16777216 * 2);
    _Float16* Bp0  = (_Float16*)take((size_t)192 * 40 * 512 * 2);
    _Float16* Bp1  = (_Float16*)take((size_t)192 * 64 * 512 * 2);
    _Float16* Bp2  = (_Float16*)take((size_t)192 * 64 * 512 * 2);

    hipMemsetAsync(counters, 0, 1024, stream);

    f32_to_f16<<<2048, 256, 0, stream>>>((const float*)d_in[0], xin, 4194304);
    f32_to_f16<<<64, 256, 0, stream>>>((const float*)d_in[1], h0h0, 65536);
    f32_to_f16<<<64, 256, 0, stream>>>((const float*)d_in[5], h0h1, 65536);
    f32_to_f16<<<64, 256, 0, stream>>>((const float*)d_in[9], h0h2, 65536);

    pack_weights<<<1920, 256, 0, stream>>>((const float*)d_in[2], (const float*)d_in[3],
                                           Bp0, 256, 40);
    pack_weights<<<3072, 256, 0, stream>>>((const float*)d_in[6], (const float*)d_in[7],
                                           Bp1, 1024, 64);
    pack_weights<<<3072, 256, 0, stream>>>((const float*)d_in[10], (const float*)d_in[11],
                                           Bp2, 1024, 64);

    float* xout = (float*)d_out;
    float* souts = xout + (size_t)16777216;

    gru_layer<<<GRIDB, 512, 0, stream>>>(xin, h0h0, (const float*)d_in[1], Bp0,
                                         (const float*)d_in[4], y0, nullptr,
                                         souts + 0, counters + 0, 256);
    gru_layer<<<GRIDB, 512, 0, stream>>>(y0, h0h1, (const float*)d_in[5], Bp1,
                                         (const float*)d_in[8], y1, nullptr,
                                         souts + 65536, counters + 16, 1024);
    gru_layer<<<GRIDB, 512, 0, stream>>>(y1, h0h2, (const float*)d_in[9], Bp2,
                                         (const float*)d_in[12], y2, xout,
                                         souts + 131072, counters + 32, 1024);
}

// Round 2
// 5272.255 us; speedup vs baseline: 2.3247x; 2.3247x over previous
//
#include <hip/hip_runtime.h>
#include <hip/hip_fp16.h>

// GRU stack: B=64, T=256, F=256, U=1024, 3 layers, reset_after=True.
// Fused 3-layer pipelined persistent kernel: 192 blocks (64 per layer).
// Layer l+1 step t waits (via L3 counter) for layer l to finish step t.
// d_in order: [0]=inputs, per layer l: [1+4l]=state, [2+4l]=W, [3+4l]=U, [4+4l]=b
// d_out: x[64,256,1024] f32, then s0,s1,s2 [64,1024] f32.

typedef _Float16 half8 __attribute__((ext_vector_type(8)));
typedef float f32x4 __attribute__((ext_vector_type(4)));

#define TSTEPS 256
#define UDIM 1024
#define G3U 3072
#define GRIDB 64   // blocks per layer

__device__ __forceinline__ f32x4 mfma16(half8 a, half8 b, f32x4 c) {
    return __builtin_amdgcn_mfma_f32_16x16x32_f16(a, b, c, 0, 0, 0);
}

// agent-scope (coherence-point) 16B load as 2x8B atomic loads: bypasses the
// non-coherent per-XCD L2 so cross-block h/y updates are always seen.
__device__ __forceinline__ half8 load_h_agent(const _Float16* p) {
    union { unsigned long long u[2]; half8 h; } un;
    const unsigned long long* q = (const unsigned long long*)p;
    un.u[0] = __hip_atomic_load(q,     __ATOMIC_RELAXED, __HIP_MEMORY_SCOPE_AGENT);
    un.u[1] = __hip_atomic_load(q + 1, __ATOMIC_RELAXED, __HIP_MEMORY_SCOPE_AGENT);
    return un.h;
}

__global__ void f32_to_f16(const float* __restrict__ src, _Float16* __restrict__ dst, int n) {
    int i = blockIdx.x * blockDim.x + threadIdx.x;
    int st = gridDim.x * blockDim.x;
    for (; i < n; i += st) dst[i] = (_Float16)src[i];
}

// Pack [W; Ur] (rows = k, cols = gate col) into MFMA B-fragment order:
// Bp[nt][kc][lane][8] with element = B[kc*32 + (lane>>4)*8 + i][nt*16 + (lane&15)]
__global__ void pack_weights(const float* __restrict__ W, const float* __restrict__ Ur,
                             _Float16* __restrict__ Bp, int KIN, int KC) {
    int idx = blockIdx.x * blockDim.x + threadIdx.x;
    int total = 192 * KC * 64;
    int st = gridDim.x * blockDim.x;
    for (; idx < total; idx += st) {
        int lane = idx & 63;
        int kc = (idx >> 6) % KC;
        int nt = idx / (KC * 64);
        int col = nt * 16 + (lane & 15);
        int k0 = kc * 32 + (lane >> 4) * 8;
        half8 v;
#pragma unroll
        for (int i = 0; i < 8; ++i) {
            int k = k0 + i;
            float f = (k < KIN) ? W[(size_t)k * G3U + col]
                                : Ur[(size_t)(k - KIN) * G3U + col];
            v[i] = (_Float16)f;
        }
        *(half8*)(Bp + (size_t)idx * 8) = v;
    }
}

struct LayerArgs {
    const _Float16* xcur;   // [B, T, KIN] fp16 input sequence (layer0: xin, else y_{l-1})
    const _Float16* h0h;    // [B, U] fp16 initial state
    const float* state;     // [B, U] f32 initial state
    const _Float16* Bp;     // packed weights [192][KC][64][8]
    const float* bias;      // [2][3072] f32
    _Float16* yown;         // [B, T, U] fp16 layer output (h recurrence source)
    float* fxout;           // final layer: d_out x area, else null
    float* sout;            // d_out state slot [B, U]
    unsigned* own_cnt;      // this layer's step counter
    const unsigned* prod_cnt; // producer layer's counter (null for layer 0)
};

using RedT = f32x4 (*)[4][2][64];

// Per-layer GRU body. Block `blk` owns gate columns {j, U+j, 2U+j},
// j in [16*blk, 16*blk+16), for ALL 64 batch rows -> sole producer of its
// 16-col h slice => 1 grid barrier per step. 8 waves K-split; LDS reduce.
// h master state in f32 registers of waves 0..3.
template <int KIN, bool XA>
__device__ __forceinline__ void gru_body(const LayerArgs& A, int blk, RedT red) {
    const int tid = threadIdx.x;
    const int lane = tid & 63;
    const int wid = tid >> 6;          // 0..7: K-split index
    const int col = lane & 15;
    const int lrow = lane >> 4;        // 0..3
    const int klane0 = lrow * 8;       // A/B fragment k offset for this lane
    const int j = blk * 16 + col;      // owned hidden unit column
    constexpr int KC = (KIN + UDIM) >> 5;  // total K chunks (40 or 64)
    constexpr int KCW = KC >> 3;           // chunks per wave
    constexpr int KINC = KIN >> 5;         // x-part chunk count
    const int ck0 = wid * KCW, ck1 = ck0 + KCW;

    const float b0z = A.bias[j],           b1z = A.bias[G3U + j];
    const float b0r = A.bias[UDIM + j],    b1r = A.bias[G3U + UDIM + j];
    const float b0h = A.bias[2*UDIM + j],  b1h = A.bias[G3U + 2*UDIM + j];

    float hreg[4] = {0.f, 0.f, 0.f, 0.f};
    if (wid < 4) {
#pragma unroll
        for (int e = 0; e < 4; ++e) {
            int m = wid * 16 + lrow * 4 + e;  // D row = (lane>>4)*4 + reg
            hreg[e] = A.state[(size_t)m * UDIM + j];
        }
    }

    const _Float16* bpz = A.Bp + (size_t)(blk)       * KC * 512 + lane * 8;
    const _Float16* bpr = A.Bp + (size_t)(64 + blk)  * KC * 512 + lane * 8;
    const _Float16* bph = A.Bp + (size_t)(128 + blk) * KC * 512 + lane * 8;

    for (int t = 0; t < TSTEPS; ++t) {
        // --- top-of-step gate: own-layer h ready + producer's y[:,t,:] ready
        if (tid == 0) {
            if (t > 0) {
                unsigned tgt = (unsigned)(GRIDB * t);
                while (__hip_atomic_load(A.own_cnt, __ATOMIC_RELAXED,
                                         __HIP_MEMORY_SCOPE_AGENT) < tgt)
                    __builtin_amdgcn_s_sleep(2);
            }
            if (XA) {
                unsigned tgt2 = (unsigned)(GRIDB * (t + 1));
                while (__hip_atomic_load(A.prod_cnt, __ATOMIC_RELAXED,
                                         __HIP_MEMORY_SCOPE_AGENT) < tgt2)
                    __builtin_amdgcn_s_sleep(2);
            }
        }
        __syncthreads();

        f32x4 accz[4], accr[4], acchx[4], acchr[4];
#pragma unroll
        for (int m4 = 0; m4 < 4; ++m4) {
            accz[m4] = (f32x4){0.f,0.f,0.f,0.f};
            accr[m4] = (f32x4){0.f,0.f,0.f,0.f};
            acchx[m4] = (f32x4){0.f,0.f,0.f,0.f};
            acchr[m4] = (f32x4){0.f,0.f,0.f,0.f};
        }
        const _Float16* xr[4];
        const _Float16* hr[4];
#pragma unroll
        for (int m4 = 0; m4 < 4; ++m4) {
            int rm = m4 * 16 + (lane & 15);   // A row = lane%16
            xr[m4] = A.xcur + ((size_t)rm * TSTEPS + t) * KIN + klane0;
            hr[m4] = (t == 0) ? (A.h0h + (size_t)rm * UDIM + klane0)
                              : (A.yown + ((size_t)rm * TSTEPS + (t - 1)) * UDIM + klane0);
        }
        // x-part chunks (acchx gets the h-gate x term)
        int cxe = ck1 < KINC ? ck1 : KINC;
#pragma unroll 2
        for (int ck = ck0; ck < cxe; ++ck) {
            half8 bz = *(const half8*)(bpz + (size_t)ck * 512);
            half8 br = *(const half8*)(bpr + (size_t)ck * 512);
            half8 bh = *(const half8*)(bph + (size_t)ck * 512);
            int off = ck * 32;
#pragma unroll
            for (int m4 = 0; m4 < 4; ++m4) {
                half8 a = XA ? load_h_agent(xr[m4] + off)
                             : *(const half8*)(xr[m4] + off);
                accz[m4]  = mfma16(a, bz, accz[m4]);
                accr[m4]  = mfma16(a, br, accr[m4]);
                acchx[m4] = mfma16(a, bh, acchx[m4]);
            }
        }
        // h-part chunks (agent-scope loads; acchr gets the h-gate rec term)
        int chs = ck0 > KINC ? ck0 : KINC;
#pragma unroll 2
        for (int ck = chs; ck < ck1; ++ck) {
            half8 bz = *(const half8*)(bpz + (size_t)ck * 512);
            half8 br = *(const half8*)(bpr + (size_t)ck * 512);
            half8 bh = *(const half8*)(bph + (size_t)ck * 512);
            int off = (ck - KINC) * 32;
#pragma unroll
            for (int m4 = 0; m4 < 4; ++m4) {
                half8 a = load_h_agent(hr[m4] + off);
                accz[m4]  = mfma16(a, bz, accz[m4]);
                accr[m4]  = mfma16(a, br, accr[m4]);
                acchr[m4] = mfma16(a, bh, acchr[m4]);
            }
        }

        // 8-way cross-wave reduction in two 64KB-buffer passes
        f32x4 fz = {0.f,0.f,0.f,0.f}, fr = {0.f,0.f,0.f,0.f};
        f32x4 fhx = {0.f,0.f,0.f,0.f}, fhr = {0.f,0.f,0.f,0.f};
        for (int p = 0; p < 2; ++p) {
#pragma unroll
            for (int m4 = 0; m4 < 4; ++m4) {
                red[wid][m4][0][lane] = p ? acchx[m4] : accz[m4];
                red[wid][m4][1][lane] = p ? acchr[m4] : accr[m4];
            }
            __syncthreads();
            if (wid < 4) {
                f32x4 s0 = {0.f,0.f,0.f,0.f}, s1 = {0.f,0.f,0.f,0.f};
#pragma unroll
                for (int s = 0; s < 8; ++s) {
                    s0 += red[s][wid][0][lane];
                    s1 += red[s][wid][1][lane];
                }
                if (p == 0) { fz = s0; fr = s1; } else { fhx = s0; fhr = s1; }
            }
            __syncthreads();
        }

        if (wid < 4) {
#pragma unroll
            for (int e = 0; e < 4; ++e) {
                float zp = fz[e] + b0z + b1z;
                float rp = fr[e] + b0r + b1r;
                float z = 1.f / (1.f + expf(-zp));
                float r = 1.f / (1.f + expf(-rp));
                float hh = tanhf(fhx[e] + b0h + r * (fhr[e] + b1h));
                float hn = z * hreg[e] + (1.f - z) * hh;
                hreg[e] = hn;
                int m = wid * 16 + lrow * 4 + e;
                size_t yi = ((size_t)m * TSTEPS + t) * UDIM + j;
                union { _Float16 f; unsigned short u; } cv;
                cv.f = (_Float16)hn;
                // pack 2 adjacent cols into one 4B agent store
                unsigned pu = (unsigned)(unsigned short)__shfl_xor((int)(unsigned)cv.u, 1, 64);
                if (!(col & 1)) {
                    unsigned val = ((unsigned)cv.u) | (pu << 16);
                    __hip_atomic_store((unsigned*)(A.yown + yi), val,
                                       __ATOMIC_RELAXED, __HIP_MEMORY_SCOPE_AGENT);
                }
                if (A.fxout) A.fxout[yi] = hn;
                if (t == TSTEPS - 1) A.sout[(size_t)m * UDIM + j] = hn;
            }
        }

        // end-of-step: drain stores (syncthreads implies per-wave vmcnt(0)),
        // then RELAXED bump — stores are agent-scope write-through, already at
        // the coherence point when vmcnt drained, so RELEASE (and its L2
        // writeback) is unnecessary.
        __syncthreads();
        if (tid == 0)
            __hip_atomic_fetch_add(A.own_cnt, 1u, __ATOMIC_RELAXED,
                                   __HIP_MEMORY_SCOPE_AGENT);
    }
}

__global__ __launch_bounds__(512, 1) void gru_fused(LayerArgs a0, LayerArgs a1, LayerArgs a2) {
    __shared__ f32x4 red[8][4][2][64]; // 64 KiB reduction buffer (shared by paths)
    int lay = blockIdx.x >> 6;
    int blk = blockIdx.x & 63;
    if (lay == 0)      gru_body<256,  false>(a0, blk, red);
    else if (lay == 1) gru_body<1024, true >(a1, blk, red);
    else               gru_body<1024, true >(a2, blk, red);
}

extern "C" void kernel_launch(void* const* d_in, const int* in_sizes, int n_in,
                              void* d_out, int out_size, void* d_ws, size_t ws_size,
                              hipStream_t stream) {
    (void)in_sizes; (void)n_in; (void)out_size; (void)ws_size;

    char* ws = (char*)d_ws;
    size_t off = 0;
    auto take = [&](size_t bytes) -> char* {
        char* p = ws + off;
        off += (bytes + 255) & ~(size_t)255;
        return p;
    };
    unsigned* counters = (unsigned*)take(1024);        // 3 counters, 256B apart
    _Float16* h0h0 = (_Float16*)take((size_t)65536 * 2);
    _Float16* h0h1 = (_Float16*)take((size_t)65536 * 2);
    _Float16* h0h2 = (_Float16*)take((size_t)65536 * 2);
    _Float16* xin  = (_Float16*)take((size_t)4194304 * 2);     // [64,256,256]
    _Float16* y0   = (_Float16*)take((size_t)16777216 * 2);    // [64,256,1024]
    _Float16* y1   = (_Float16*)take((size_t)16777216 * 2);
    _Float16* y2   = (_Float16*)take((size_t)16777216 * 2);
    _Float16* Bp0  = (_Float16*)take((size_t)192 * 40 * 512 * 2);
    _Float16* Bp1  = (_Float16*)take((size_t)192 * 64 * 512 * 2);
    _Float16* Bp2  = (_Float16*)take((size_t)192 * 64 * 512 * 2);

    hipMemsetAsync(counters, 0, 1024, stream);

    f32_to_f16<<<2048, 256, 0, stream>>>((const float*)d_in[0], xin, 4194304);
    f32_to_f16<<<64, 256, 0, stream>>>((const float*)d_in[1], h0h0, 65536);
    f32_to_f16<<<64, 256, 0, stream>>>((const float*)d_in[5], h0h1, 65536);
    f32_to_f16<<<64, 256, 0, stream>>>((const float*)d_in[9], h0h2, 65536);

    pack_weights<<<1920, 256, 0, stream>>>((const float*)d_in[2], (const float*)d_in[3],
                                           Bp0, 256, 40);
    pack_weights<<<3072, 256, 0, stream>>>((const float*)d_in[6], (const float*)d_in[7],
                                           Bp1, 1024, 64);
    pack_weights<<<3072, 256, 0, stream>>>((const float*)d_in[10], (const float*)d_in[11],
                                           Bp2, 1024, 64);

    float* xout = (float*)d_out;
    float* souts = xout + (size_t)16777216;

    LayerArgs a0 = { xin, h0h0, (const float*)d_in[1], Bp0, (const float*)d_in[4],
                     y0, nullptr, souts + 0, counters + 0, nullptr };
    LayerArgs a1 = { y0, h0h1, (const float*)d_in[5], Bp1, (const float*)d_in[8],
                     y1, nullptr, souts + 65536, counters + 64, counters + 0 };
    LayerArgs a2 = { y1, h0h2, (const float*)d_in[9], Bp2, (const float*)d_in[12],
                     y2, xout, souts + 131072, counters + 128, counters + 64 };

    gru_fused<<<192, 512, 0, stream>>>(a0, a1, a2);
}

// Round 3
// 4746.552 us; speedup vs baseline: 2.5821x; 1.1108x over previous
//
#include <hip/hip_runtime.h>
#include <hip/hip_fp16.h>

// GRU stack: B=64, T=256, F=256, U=1024, 3 layers, reset_after=True.
// Fused 3-layer pipelined persistent kernel: 192 blocks (64 per layer).
// Synchronization via distributed per-block flag lines (no atomic contention):
//   - block b of layer l stores step count to flags_l[b] (own 128B line)
//   - h-waves poll own-layer flags (64 lanes, 1 flag each) before h loads
//   - x-waves poll producer-layer flags before x loads
// d_in order: [0]=inputs, per layer l: [1+4l]=state, [2+4l]=W, [3+4l]=U, [4+4l]=b
// d_out: x[64,256,1024] f32, then s0,s1,s2 [64,1024] f32.

typedef _Float16 half8 __attribute__((ext_vector_type(8)));
typedef float f32x4 __attribute__((ext_vector_type(4)));

#define TSTEPS 256
#define UDIM 1024
#define G3U 3072
#define GRIDB 64   // blocks per layer

__device__ __forceinline__ f32x4 mfma16(half8 a, half8 b, f32x4 c) {
    return __builtin_amdgcn_mfma_f32_16x16x32_f16(a, b, c, 0, 0, 0);
}

// agent-scope (coherence-point) 16B load as 2x8B atomic loads: bypasses the
// non-coherent per-XCD L2 so cross-block h/y updates are always seen.
__device__ __forceinline__ half8 load_h_agent(const _Float16* p) {
    union { unsigned long long u[2]; half8 h; } un;
    const unsigned long long* q = (const unsigned long long*)p;
    un.u[0] = __hip_atomic_load(q,     __ATOMIC_RELAXED, __HIP_MEMORY_SCOPE_AGENT);
    un.u[1] = __hip_atomic_load(q + 1, __ATOMIC_RELAXED, __HIP_MEMORY_SCOPE_AGENT);
    return un.h;
}

// Poll 64 per-block flags (128B apart) until all >= tgt. Per-wave: lane i
// watches flag i. No serialization on arrival (each block stores its own line).
__device__ __forceinline__ void poll_flags(const unsigned* f, unsigned tgt) {
    const unsigned* p = f + (threadIdx.x & 63) * 32;
    for (;;) {
        unsigned v = __hip_atomic_load(p, __ATOMIC_RELAXED, __HIP_MEMORY_SCOPE_AGENT);
        if (__all((int)(v >= tgt))) break;
        __builtin_amdgcn_s_sleep(2);
    }
    asm volatile("" ::: "memory");  // no gated-load hoisting above the spin
}

__global__ void f32_to_f16(const float* __restrict__ src, _Float16* __restrict__ dst, int n) {
    int i = blockIdx.x * blockDim.x + threadIdx.x;
    int st = gridDim.x * blockDim.x;
    for (; i < n; i += st) dst[i] = (_Float16)src[i];
}

// Pack [W; Ur] (rows = k, cols = gate col) into MFMA B-fragment order:
// Bp[nt][kc][lane][8] with element = B[kc*32 + (lane>>4)*8 + i][nt*16 + (lane&15)]
__global__ void pack_weights(const float* __restrict__ W, const float* __restrict__ Ur,
                             _Float16* __restrict__ Bp, int KIN, int KC) {
    int idx = blockIdx.x * blockDim.x + threadIdx.x;
    int total = 192 * KC * 64;
    int st = gridDim.x * blockDim.x;
    for (; idx < total; idx += st) {
        int lane = idx & 63;
        int kc = (idx >> 6) % KC;
        int nt = idx / (KC * 64);
        int col = nt * 16 + (lane & 15);
        int k0 = kc * 32 + (lane >> 4) * 8;
        half8 v;
#pragma unroll
        for (int i = 0; i < 8; ++i) {
            int k = k0 + i;
            float f = (k < KIN) ? W[(size_t)k * G3U + col]
                                : Ur[(size_t)(k - KIN) * G3U + col];
            v[i] = (_Float16)f;
        }
        *(half8*)(Bp + (size_t)idx * 8) = v;
    }
}

struct LayerArgs {
    const _Float16* xcur;     // [B, T, KIN] fp16 input sequence
    const _Float16* h0h;      // [B, U] fp16 initial state
    const float* state;       // [B, U] f32 initial state
    const _Float16* Bp;       // packed weights [192][KC][64][8]
    const float* bias;        // [2][3072] f32
    _Float16* yown;           // [B, T, U] fp16 layer output (h recurrence source)
    float* fxout;             // final layer: d_out x area, else null
    float* sout;              // d_out state slot [B, U]
    unsigned* own_flags;      // 64 flags, 128B stride
    const unsigned* prod_flags; // producer layer's flags (null for layer 0)
};

// Per-layer GRU body. Block `blk` owns gate columns {j, U+j, 2U+j},
// j in [16*blk, 16*blk+16), for ALL 64 batch rows. 8 waves K-split.
// For KIN==UDIM the K-split is exact: waves 0-3 = x-part only (poll producer),
// waves 4-7 = h-part only (poll own flags). Single-pass LDS reduce (NS slots),
// 2 syncthreads per step. h master f32 state in waves 0-3 registers.
template <int KIN, bool XA>
__device__ __forceinline__ void gru_body(const LayerArgs& A, int blk, f32x4* red) {
    const int tid = threadIdx.x;
    const int lane = tid & 63;
    const int wid = tid >> 6;          // 0..7: K-split index
    const int col = lane & 15;
    const int lrow = lane >> 4;        // 0..3
    const int klane0 = lrow * 8;       // A/B fragment k offset for this lane
    const int j = blk * 16 + col;      // owned hidden unit column
    constexpr int KC = (KIN + UDIM) >> 5;  // total K chunks (40 or 64)
    constexpr int KCW = KC >> 3;           // chunks per wave
    constexpr int KINC = KIN >> 5;         // x-part chunk count
    constexpr int NS = (KIN == UDIM) ? 3 : 4;  // reduce slots
    constexpr int HS = (NS == 3) ? 2 : 3;      // slot for h-gate recurrent part
    const int ck0 = wid * KCW, ck1 = ck0 + KCW;
    const bool has_x = ck0 < KINC;
    const bool has_h = ck1 > KINC;

    const float bsz = A.bias[j] + A.bias[G3U + j];
    const float bsr = A.bias[UDIM + j] + A.bias[G3U + UDIM + j];
    const float b0h = A.bias[2*UDIM + j], b1h = A.bias[G3U + 2*UDIM + j];

    float hreg[4] = {0.f, 0.f, 0.f, 0.f};
    if (wid < 4) {
#pragma unroll
        for (int e = 0; e < 4; ++e) {
            int m = wid * 16 + lrow * 4 + e;  // D row = (lane>>4)*4 + reg
            hreg[e] = A.state[(size_t)m * UDIM + j];
        }
    }

    const _Float16* bpz = A.Bp + (size_t)(blk)       * KC * 512 + lane * 8;
    const _Float16* bpr = A.Bp + (size_t)(64 + blk)  * KC * 512 + lane * 8;
    const _Float16* bph = A.Bp + (size_t)(128 + blk) * KC * 512 + lane * 8;

    for (int t = 0; t < TSTEPS; ++t) {
        f32x4 acc[4][4];  // [slot][m4]; slot 3 unused when NS==3
#pragma unroll
        for (int s = 0; s < 4; ++s)
#pragma unroll
            for (int m4 = 0; m4 < 4; ++m4)
                acc[s][m4] = (f32x4){0.f, 0.f, 0.f, 0.f};

        const _Float16* xr[4];
        const _Float16* hr[4];
#pragma unroll
        for (int m4 = 0; m4 < 4; ++m4) {
            int rm = m4 * 16 + (lane & 15);   // A row = lane%16
            xr[m4] = A.xcur + ((size_t)rm * TSTEPS + t) * KIN + klane0;
            hr[m4] = (t == 0) ? (A.h0h + (size_t)rm * UDIM + klane0)
                              : (A.yown + ((size_t)rm * TSTEPS + (t - 1)) * UDIM + klane0);
        }

        // ---- x-part: gate on producer only (x never reads own-layer h)
        if (XA && has_x) poll_flags(A.prod_flags, (unsigned)(t + 1));
        int cxe = ck1 < KINC ? ck1 : KINC;
#pragma unroll 2
        for (int ck = ck0; ck < cxe; ++ck) {
            half8 bz = *(const half8*)(bpz + (size_t)ck * 512);
            half8 br = *(const half8*)(bpr + (size_t)ck * 512);
            half8 bh = *(const half8*)(bph + (size_t)ck * 512);
            int off = ck * 32;
#pragma unroll
            for (int m4 = 0; m4 < 4; ++m4) {
                half8 a = XA ? load_h_agent(xr[m4] + off)
                             : *(const half8*)(xr[m4] + off);
                acc[0][m4] = mfma16(a, bz, acc[0][m4]);
                acc[1][m4] = mfma16(a, br, acc[1][m4]);
                acc[2][m4] = mfma16(a, bh, acc[2][m4]);
            }
        }
        // ---- h-part: gate on own-layer flags (all blocks finished step t-1)
        if (has_h && t > 0) poll_flags(A.own_flags, (unsigned)t);
        int chs = ck0 > KINC ? ck0 : KINC;
#pragma unroll 2
        for (int ck = chs; ck < ck1; ++ck) {
            half8 bz = *(const half8*)(bpz + (size_t)ck * 512);
            half8 br = *(const half8*)(bpr + (size_t)ck * 512);
            half8 bh = *(const half8*)(bph + (size_t)ck * 512);
            int off = (ck - KINC) * 32;
#pragma unroll
            for (int m4 = 0; m4 < 4; ++m4) {
                half8 a = load_h_agent(hr[m4] + off);
                acc[0][m4] = mfma16(a, bz, acc[0][m4]);
                acc[1][m4] = mfma16(a, br, acc[1][m4]);
                acc[HS][m4] = mfma16(a, bh, acc[HS][m4]);
            }
        }

        // ---- single-pass cross-wave reduce: red[s_wave][m4][slot][lane]
#pragma unroll
        for (int m4 = 0; m4 < 4; ++m4)
#pragma unroll
            for (int s = 0; s < NS; ++s)
                red[(size_t)(((wid * 4 + m4) * NS + s) * 64 + lane)] = acc[s][m4];
        __syncthreads();  // sync A

        if (wid < 4) {
            f32x4 fz = {0.f,0.f,0.f,0.f}, fr = {0.f,0.f,0.f,0.f};
            f32x4 fhx = {0.f,0.f,0.f,0.f}, fhr = {0.f,0.f,0.f,0.f};
#pragma unroll
            for (int s = 0; s < 8; ++s) {
                fz += red[(size_t)(((s * 4 + wid) * NS + 0) * 64 + lane)];
                fr += red[(size_t)(((s * 4 + wid) * NS + 1) * 64 + lane)];
                if (NS == 4) {
                    fhx += red[(size_t)(((s * 4 + wid) * NS + 2) * 64 + lane)];
                    fhr += red[(size_t)(((s * 4 + wid) * NS + 3) * 64 + lane)];
                } else {
                    f32x4 v = red[(size_t)(((s * 4 + wid) * NS + 2) * 64 + lane)];
                    if (s < 4) fhx += v; else fhr += v;
                }
            }
#pragma unroll
            for (int e = 0; e < 4; ++e) {
                float zp = fz[e] + bsz;
                float rp = fr[e] + bsr;
                float z = 1.f / (1.f + __expf(-zp));
                float r = 1.f / (1.f + __expf(-rp));
                float ha = fhx[e] + b0h + r * (fhr[e] + b1h);
                float hh = 2.f / (1.f + __expf(-2.f * ha)) - 1.f;  // tanh
                float hn = z * hreg[e] + (1.f - z) * hh;
                hreg[e] = hn;
                int m = wid * 16 + lrow * 4 + e;
                size_t yi = ((size_t)m * TSTEPS + t) * UDIM + j;
                union { _Float16 f; unsigned short u; } cv;
                cv.f = (_Float16)hn;
                // pack 2 adjacent cols into one 4B agent store
                unsigned pu = (unsigned)(unsigned short)__shfl_xor((int)(unsigned)cv.u, 1, 64);
                if (!(col & 1)) {
                    unsigned val = ((unsigned)cv.u) | (pu << 16);
                    __hip_atomic_store((unsigned*)(A.yown + yi), val,
                                       __ATOMIC_RELAXED, __HIP_MEMORY_SCOPE_AGENT);
                }
                if (A.fxout) A.fxout[yi] = hn;
                if (t == TSTEPS - 1) A.sout[(size_t)m * UDIM + j] = hn;
            }
        }

        // sync B: (a) reduce reads done -> red reusable, (b) every wave's
        // agent h-stores drained (syncthreads implies per-wave vmcnt(0)).
        __syncthreads();
        if (tid == 0)
            __hip_atomic_store(A.own_flags + blk * 32, (unsigned)(t + 1),
                               __ATOMIC_RELAXED, __HIP_MEMORY_SCOPE_AGENT);
    }
}

__global__ __launch_bounds__(512, 1) void gru_fused(LayerArgs a0, LayerArgs a1, LayerArgs a2) {
    __shared__ f32x4 red[8192];  // 128 KiB (layer0 path uses all; U-layers 96 KiB)
    int lay = blockIdx.x >> 6;
    int blk = blockIdx.x & 63;
    if (lay == 0)      gru_body<256,  false>(a0, blk, red);
    else if (lay == 1) gru_body<1024, true >(a1, blk, red);
    else               gru_body<1024, true >(a2, blk, red);
}

extern "C" void kernel_launch(void* const* d_in, const int* in_sizes, int n_in,
                              void* d_out, int out_size, void* d_ws, size_t ws_size,
                              hipStream_t stream) {
    (void)in_sizes; (void)n_in; (void)out_size; (void)ws_size;

    char* ws = (char*)d_ws;
    size_t off = 0;
    auto take = [&](size_t bytes) -> char* {
        char* p = ws + off;
        off += (bytes + 255) & ~(size_t)255;
        return p;
    };
    unsigned* flags = (unsigned*)take(32768);  // 3 layers x 64 flags x 128B
    _Float16* h0h0 = (_Float16*)take((size_t)65536 * 2);
    _Float16* h0h1 = (_Float16*)take((size_t)65536 * 2);
    _Float16* h0h2 = (_Float16*)take((size_t)65536 * 2);
    _Float16* xin  = (_Float16*)take((size_t)4194304 * 2);     // [64,256,256]
    _Float16* y0   = (_Float16*)take((size_t)16777216 * 2);    // [64,256,1024]
    _Float16* y1   = (_Float16*)take((size_t)16777216 * 2);
    _Float16* y2   = (_Float16*)take((size_t)16777216 * 2);
    _Float16* Bp0  = (_Float16*)take((size_t)192 * 40 * 512 * 2);
    _Float16* Bp1  = (_Float16*)take((size_t)192 * 64 * 512 * 2);
    _Float16* Bp2  = (_Float16*)take((size_t)192 * 64 * 512 * 2);

    hipMemsetAsync(flags, 0, 32768, stream);

    f32_to_f16<<<2048, 256, 0, stream>>>((const float*)d_in[0], xin, 4194304);
    f32_to_f16<<<64, 256, 0, stream>>>((const float*)d_in[1], h0h0, 65536);
    f32_to_f16<<<64, 256, 0, stream>>>((const float*)d_in[5], h0h1, 65536);
    f32_to_f16<<<64, 256, 0, stream>>>((const float*)d_in[9], h0h2, 65536);

    pack_weights<<<1920, 256, 0, stream>>>((const float*)d_in[2], (const float*)d_in[3],
                                           Bp0, 256, 40);
    pack_weights<<<3072, 256, 0, stream>>>((const float*)d_in[6], (const float*)d_in[7],
                                           Bp1, 1024, 64);
    pack_weights<<<3072, 256, 0, stream>>>((const float*)d_in[10], (const float*)d_in[11],
                                           Bp2, 1024, 64);

    float* xout = (float*)d_out;
    float* souts = xout + (size_t)16777216;

    unsigned* flags0 = flags;          // 64 x 32 u32
    unsigned* flags1 = flags + 2048;
    unsigned* flags2 = flags + 4096;

    LayerArgs a0 = { xin, h0h0, (const float*)d_in[1], Bp0, (const float*)d_in[4],
                     y0, nullptr, souts + 0, flags0, nullptr };
    LayerArgs a1 = { y0, h0h1, (const float*)d_in[5], Bp1, (const float*)d_in[8],
                     y1, nullptr, souts + 65536, flags1, flags0 };
    LayerArgs a2 = { y1, h0h2, (const float*)d_in[9], Bp2, (const float*)d_in[12],
                     y2, xout, souts + 131072, flags2, flags1 };

    gru_fused<<<192, 512, 0, stream>>>(a0, a1, a2);
}

// Round 5
// 4333.590 us; speedup vs baseline: 2.8282x; 1.0953x over previous
//
#include <hip/hip_runtime.h>
#include <hip/hip_fp16.h>

// GRU stack: B=64, T=256, F=256, U=1024, 3 layers, reset_after=True.
// Fused 3-layer pipelined persistent kernel: 192 blocks (64 per layer).
// R5 = R3 (proven-correct) + VGPR-resident weights: each wave preloads its
// K-slice of the packed weights (96 VGPRs/lane) before the t-loop, removing
// the per-step ~14.6MB/step L2-miss weight refetch that dominated step time.
// Sync via distributed per-block flag lines (no atomic contention).
// d_in order: [0]=inputs, per layer l: [1+4l]=state, [2+4l]=W, [3+4l]=U, [4+4l]=b
// d_out: x[64,256,1024] f32, then s0,s1,s2 [64,1024] f32.

typedef _Float16 half8 __attribute__((ext_vector_type(8)));
typedef float f32x4 __attribute__((ext_vector_type(4)));

#define TSTEPS 256
#define UDIM 1024
#define G3U 3072
#define GRIDB 64   // blocks per layer

__device__ __forceinline__ f32x4 mfma16(half8 a, half8 b, f32x4 c) {
    return __builtin_amdgcn_mfma_f32_16x16x32_f16(a, b, c, 0, 0, 0);
}

// agent-scope (coherence-point) 16B load as 2x8B atomic loads: bypasses the
// non-coherent per-XCD L1 so cross-block h/y updates are always seen.
__device__ __forceinline__ half8 load_h_agent(const _Float16* p) {
    union { unsigned long long u[2]; half8 h; } un;
    const unsigned long long* q = (const unsigned long long*)p;
    un.u[0] = __hip_atomic_load(q,     __ATOMIC_RELAXED, __HIP_MEMORY_SCOPE_AGENT);
    un.u[1] = __hip_atomic_load(q + 1, __ATOMIC_RELAXED, __HIP_MEMORY_SCOPE_AGENT);
    return un.h;
}

// Poll 64 per-block flags (128B apart) until all >= tgt. Per-wave: lane i
// watches flag i. No serialization on arrival (each block owns its line).
__device__ __forceinline__ void poll_flags(const unsigned* f, unsigned tgt) {
    const unsigned* p = f + (threadIdx.x & 63) * 32;
    for (;;) {
        unsigned v = __hip_atomic_load(p, __ATOMIC_RELAXED, __HIP_MEMORY_SCOPE_AGENT);
        if (__all((int)(v >= tgt))) break;
        __builtin_amdgcn_s_sleep(2);
    }
    asm volatile("" ::: "memory");  // no gated-load hoisting above the spin
}

__global__ void f32_to_f16(const float* __restrict__ src, _Float16* __restrict__ dst, int n) {
    int i = blockIdx.x * blockDim.x + threadIdx.x;
    int st = gridDim.x * blockDim.x;
    for (; i < n; i += st) dst[i] = (_Float16)src[i];
}

// Pack [W; Ur] (rows = k, cols = gate col) into MFMA B-fragment order:
// Bp[nt][kc][lane][8] with element = B[kc*32 + (lane>>4)*8 + i][nt*16 + (lane&15)]
__global__ void pack_weights(const float* __restrict__ W, const float* __restrict__ Ur,
                             _Float16* __restrict__ Bp, int KIN, int KC) {
    int idx = blockIdx.x * blockDim.x + threadIdx.x;
    int total = 192 * KC * 64;
    int st = gridDim.x * blockDim.x;
    for (; idx < total; idx += st) {
        int lane = idx & 63;
        int kc = (idx >> 6) % KC;
        int nt = idx / (KC * 64);
        int col = nt * 16 + (lane & 15);
        int k0 = kc * 32 + (lane >> 4) * 8;
        half8 v;
#pragma unroll
        for (int i = 0; i < 8; ++i) {
            int k = k0 + i;
            float f = (k < KIN) ? W[(size_t)k * G3U + col]
                                : Ur[(size_t)(k - KIN) * G3U + col];
            v[i] = (_Float16)f;
        }
        *(half8*)(Bp + (size_t)idx * 8) = v;
    }
}

struct LayerArgs {
    const _Float16* xcur;     // [B, T, KIN] fp16 input sequence
    const _Float16* h0h;      // [B, U] fp16 initial state
    const float* state;       // [B, U] f32 initial state
    const _Float16* Bp;       // packed weights [192][KC][64][8]
    const float* bias;        // [2][3072] f32
    _Float16* yown;           // [B, T, U] fp16 layer output (h recurrence source)
    float* fxout;             // final layer: d_out x area, else null
    float* sout;              // d_out state slot [B, U]
    unsigned* own_flags;      // 64 flags, 128B stride
    const unsigned* prod_flags; // producer layer's flags (null for layer 0)
};

// Per-layer GRU body. Block `blk` owns gate columns {j, U+j, 2U+j},
// j in [16*blk, 16*blk+16), for ALL 64 batch rows. 8 waves K-split; for
// KIN==UDIM waves 0-3 = x-part only (poll producer), 4-7 = h-part only
// (poll own flags). Weights live in registers (preloaded once). Single-pass
// LDS reduce; h master f32 state in waves 0-3 registers. 2 syncthreads/step.
template <int KIN, bool XA>
__device__ __forceinline__ void gru_body(const LayerArgs& A, int blk, f32x4* red) {
    const int tid = threadIdx.x;
    const int lane = tid & 63;
    const int wid = tid >> 6;          // 0..7: K-split index
    const int col = lane & 15;
    const int lrow = lane >> 4;        // 0..3
    const int klane0 = lrow * 8;       // A/B fragment k offset for this lane
    const int j = blk * 16 + col;      // owned hidden unit column
    constexpr int KC = (KIN + UDIM) >> 5;  // total K chunks (40 or 64)
    constexpr int KCW = KC >> 3;           // chunks per wave
    constexpr int KINC = KIN >> 5;         // x-part chunk count
    constexpr int NS = (KIN == UDIM) ? 3 : 4;  // reduce slots
    constexpr int HS = (NS == 3) ? 2 : 3;      // slot for h-gate recurrent part
    const int ck0 = wid * KCW;
    const int ck1 = ck0 + KCW;
    const bool has_x = ck0 < KINC;
    const bool has_h = ck1 > KINC;

    const float bsz = A.bias[j] + A.bias[G3U + j];
    const float bsr = A.bias[UDIM + j] + A.bias[G3U + UDIM + j];
    const float b0h = A.bias[2*UDIM + j], b1h = A.bias[G3U + 2*UDIM + j];

    float hreg[4] = {0.f, 0.f, 0.f, 0.f};
    if (wid < 4) {
#pragma unroll
        for (int e = 0; e < 4; ++e) {
            int m = wid * 16 + lrow * 4 + e;  // D row = (lane>>4)*4 + reg
            hreg[e] = A.state[(size_t)m * UDIM + j];
        }
    }

    // ---- preload this wave's weight K-slice into registers (loop-invariant;
    // 3 gates x KCW chunks x 16B/lane = 96 VGPRs for U-layers, 60 for L0) ----
    half8 wz[KCW], wrg[KCW], wh[KCW];
    {
        const _Float16* bpz = A.Bp + (size_t)(blk)       * KC * 512 + lane * 8;
        const _Float16* bpr = A.Bp + (size_t)(64 + blk)  * KC * 512 + lane * 8;
        const _Float16* bph = A.Bp + (size_t)(128 + blk) * KC * 512 + lane * 8;
#pragma unroll
        for (int c = 0; c < KCW; ++c) {
            wz[c]  = *(const half8*)(bpz + (size_t)(ck0 + c) * 512);
            wrg[c] = *(const half8*)(bpr + (size_t)(ck0 + c) * 512);
            wh[c]  = *(const half8*)(bph + (size_t)(ck0 + c) * 512);
        }
    }

    for (int t = 0; t < TSTEPS; ++t) {
        f32x4 acc[NS][4];  // [slot][m4]
#pragma unroll
        for (int s = 0; s < NS; ++s)
#pragma unroll
            for (int m4 = 0; m4 < 4; ++m4)
                acc[s][m4] = (f32x4){0.f, 0.f, 0.f, 0.f};

        const _Float16* xr[4];
        const _Float16* hr[4];
#pragma unroll
        for (int m4 = 0; m4 < 4; ++m4) {
            int rm = m4 * 16 + (lane & 15);   // A row = lane%16
            xr[m4] = A.xcur + ((size_t)rm * TSTEPS + t) * KIN + klane0;
            hr[m4] = (t == 0) ? (A.h0h + (size_t)rm * UDIM + klane0)
                              : (A.yown + ((size_t)rm * TSTEPS + (t - 1)) * UDIM + klane0);
        }

        // ---- x-part: gate on producer only (x never reads own-layer h)
        if (XA && has_x) poll_flags(A.prod_flags, (unsigned)(t + 1));
#pragma unroll
        for (int c = 0; c < KCW; ++c) {
            int ck = ck0 + c;
            if (ck < KINC) {      // wave-uniform
                int off = ck * 32;
#pragma unroll
                for (int m4 = 0; m4 < 4; ++m4) {
                    half8 a = XA ? load_h_agent(xr[m4] + off)
                                 : *(const half8*)(xr[m4] + off);
                    acc[0][m4] = mfma16(a, wz[c],  acc[0][m4]);
                    acc[1][m4] = mfma16(a, wrg[c], acc[1][m4]);
                    acc[2][m4] = mfma16(a, wh[c],  acc[2][m4]);
                }
            }
        }
        // ---- h-part: gate on own-layer flags (all blocks finished step t-1)
        if (has_h && t > 0) poll_flags(A.own_flags, (unsigned)t);
#pragma unroll
        for (int c = 0; c < KCW; ++c) {
            int ck = ck0 + c;
            if (ck >= KINC) {     // wave-uniform
                int off = (ck - KINC) * 32;
#pragma unroll
                for (int m4 = 0; m4 < 4; ++m4) {
                    half8 a = load_h_agent(hr[m4] + off);
                    acc[0][m4]  = mfma16(a, wz[c],  acc[0][m4]);
                    acc[1][m4]  = mfma16(a, wrg[c], acc[1][m4]);
                    acc[HS][m4] = mfma16(a, wh[c],  acc[HS][m4]);
                }
            }
        }

        // ---- single-pass cross-wave reduce: red[(wid*4+m4)*NS+s][lane]
#pragma unroll
        for (int m4 = 0; m4 < 4; ++m4)
#pragma unroll
            for (int s = 0; s < NS; ++s)
                red[(size_t)(((wid * 4 + m4) * NS + s) * 64 + lane)] = acc[s][m4];
        __syncthreads();  // sync A

        if (wid < 4) {
            f32x4 fz = {0.f,0.f,0.f,0.f}, fr = {0.f,0.f,0.f,0.f};
            f32x4 fhx = {0.f,0.f,0.f,0.f}, fhr = {0.f,0.f,0.f,0.f};
#pragma unroll
            for (int s = 0; s < 8; ++s) {
                fz += red[(size_t)(((s * 4 + wid) * NS + 0) * 64 + lane)];
                fr += red[(size_t)(((s * 4 + wid) * NS + 1) * 64 + lane)];
                if (NS == 4) {
                    fhx += red[(size_t)(((s * 4 + wid) * NS + 2) * 64 + lane)];
                    fhr += red[(size_t)(((s * 4 + wid) * NS + 3) * 64 + lane)];
                } else {
                    f32x4 v = red[(size_t)(((s * 4 + wid) * NS + 2) * 64 + lane)];
                    if (s < 4) fhx += v; else fhr += v;
                }
            }
#pragma unroll
            for (int e = 0; e < 4; ++e) {
                float zp = fz[e] + bsz;
                float rp = fr[e] + bsr;
                float z = 1.f / (1.f + __expf(-zp));
                float r = 1.f / (1.f + __expf(-rp));
                float ha = fhx[e] + b0h + r * (fhr[e] + b1h);
                float hh = 2.f / (1.f + __expf(-2.f * ha)) - 1.f;  // tanh
                float hn = z * hreg[e] + (1.f - z) * hh;
                hreg[e] = hn;
                int m = wid * 16 + lrow * 4 + e;
                size_t yi = ((size_t)m * TSTEPS + t) * UDIM + j;
                union { _Float16 f; unsigned short u; } cv;
                cv.f = (_Float16)hn;
                // pack 2 adjacent cols into one 4B agent store
                unsigned pu = (unsigned)(unsigned short)__shfl_xor((int)(unsigned)cv.u, 1, 64);
                if (!(col & 1)) {
                    unsigned val = ((unsigned)cv.u) | (pu << 16);
                    __hip_atomic_store((unsigned*)(A.yown + yi), val,
                                       __ATOMIC_RELAXED, __HIP_MEMORY_SCOPE_AGENT);
                }
                if (A.fxout) A.fxout[yi] = hn;
                if (t == TSTEPS - 1) A.sout[(size_t)m * UDIM + j] = hn;
            }
        }

        // sync B: (a) reduce reads done -> red reusable, (b) every wave's
        // agent h-stores drained (syncthreads implies per-wave vmcnt(0)).
        __syncthreads();
        if (tid == 0)
            __hip_atomic_store(A.own_flags + blk * 32, (unsigned)(t + 1),
                               __ATOMIC_RELAXED, __HIP_MEMORY_SCOPE_AGENT);
    }
}

__global__ __launch_bounds__(512, 1) void gru_fused(LayerArgs a0, LayerArgs a1, LayerArgs a2) {
    __shared__ f32x4 red[8192];  // 128 KiB (layer0 path uses all; U-layers 96 KiB)
    int lay = blockIdx.x >> 6;
    int blk = blockIdx.x & 63;
    if (lay == 0)      gru_body<256,  false>(a0, blk, red);
    else if (lay == 1) gru_body<1024, true >(a1, blk, red);
    else               gru_body<1024, true >(a2, blk, red);
}

extern "C" void kernel_launch(void* const* d_in, const int* in_sizes, int n_in,
                              void* d_out, int out_size, void* d_ws, size_t ws_size,
                              hipStream_t stream) {
    (void)in_sizes; (void)n_in; (void)out_size; (void)ws_size;

    char* ws = (char*)d_ws;
    size_t off = 0;
    auto take = [&](size_t bytes) -> char* {
        char* p = ws + off;
        off += (bytes + 255) & ~(size_t)255;
        return p;
    };
    unsigned* flags = (unsigned*)take(32768);  // 3 layers x 64 flags x 128B
    _Float16* h0h0 = (_Float16*)take((size_t)65536 * 2);
    _Float16* h0h1 = (_Float16*)take((size_t)65536 * 2);
    _Float16* h0h2 = (_Float16*)take((size_t)65536 * 2);
    _Float16* xin  = (_Float16*)take((size_t)4194304 * 2);     // [64,256,256]
    _Float16* y0   = (_Float16*)take((size_t)16777216 * 2);    // [64,256,1024]
    _Float16* y1   = (_Float16*)take((size_t)16777216 * 2);
    _Float16* y2   = (_Float16*)take((size_t)16777216 * 2);
    _Float16* Bp0  = (_Float16*)take((size_t)192 * 40 * 512 * 2);
    _Float16* Bp1  = (_Float16*)take((size_t)192 * 64 * 512 * 2);
    _Float16* Bp2  = (_Float16*)take((size_t)192 * 64 * 512 * 2);

    hipMemsetAsync(flags, 0, 32768, stream);

    f32_to_f16<<<2048, 256, 0, stream>>>((const float*)d_in[0], xin, 4194304);
    f32_to_f16<<<64, 256, 0, stream>>>((const float*)d_in[1], h0h0, 65536);
    f32_to_f16<<<64, 256, 0, stream>>>((const float*)d_in[5], h0h1, 65536);
    f32_to_f16<<<64, 256, 0, stream>>>((const float*)d_in[9], h0h2, 65536);

    pack_weights<<<1920, 256, 0, stream>>>((const float*)d_in[2], (const float*)d_in[3],
                                           Bp0, 256, 40);
    pack_weights<<<3072, 256, 0, stream>>>((const float*)d_in[6], (const float*)d_in[7],
                                           Bp1, 1024, 64);
    pack_weights<<<3072, 256, 0, stream>>>((const float*)d_in[10], (const float*)d_in[11],
                                           Bp2, 1024, 64);

    float* xout = (float*)d_out;
    float* souts = xout + (size_t)16777216;

    unsigned* flags0 = flags;          // 64 x 32 u32
    unsigned* flags1 = flags + 2048;
    unsigned* flags2 = flags + 4096;

    LayerArgs a0 = { xin, h0h0, (const float*)d_in[1], Bp0, (const float*)d_in[4],
                     y0, nullptr, souts + 0, flags0, nullptr };
    LayerArgs a1 = { y0, h0h1, (const float*)d_in[5], Bp1, (const float*)d_in[8],
                     y1, nullptr, souts + 65536, flags1, flags0 };
    LayerArgs a2 = { y1, h0h2, (const float*)d_in[9], Bp2, (const float*)d_in[12],
                     y2, xout, souts + 131072, flags2, flags1 };

    gru_fused<<<192, 512, 0, stream>>>(a0, a1, a2);
}